// Round 11
// baseline (268.964 us; speedup 1.0000x reference)
//
#include <hip/hip_runtime.h>
#include <stdint.h>

#define HIDDEN 1024
#define HEADS 16
#define HEAD_DIM 64
#define BATCH 4
#define SEQ 2048
#define ROWS (BATCH * SEQ) /* 8192 */

typedef float f32x4 __attribute__((ext_vector_type(4)));
typedef short bf16x8 __attribute__((ext_vector_type(8))); // 8 bf16 = 4 VGPRs

__device__ __forceinline__ uint16_t f32_to_bf16_rne(float f) {
    uint32_t u = __float_as_uint(f);
    uint32_t r = u + 0x7FFFu + ((u >> 16) & 1u);
    return (uint16_t)(r >> 16);
}
__device__ __forceinline__ float bf16_to_f32(uint16_t u) {
    return __uint_as_float(((uint32_t)u) << 16);
}
// HW packed fp32->bf16 RNE: dst = {bf16(lo), bf16(hi)} (lo in bits 0-15).
__device__ __forceinline__ uint32_t cvt_pk_bf16(float lo, float hi) {
    uint32_t r;
    asm("v_cvt_pk_bf16_f32 %0, %1, %2" : "=v"(r) : "v"(lo), "v"(hi));
    return r;
}

// ---------------------------------------------------------------------------
// Kernel 0: W[K][N] fp32 -> Wt[N][K] bf16, z in {Wk, Wv} only (Wq stays fp32)
// ---------------------------------------------------------------------------
__global__ __launch_bounds__(256) void wt_kernel(const float* __restrict__ Wk,
                                                 const float* __restrict__ Wv,
                                                 uint16_t* __restrict__ Wt) {
    const float* W = blockIdx.z == 0 ? Wk : Wv;
    uint16_t* out = Wt + (size_t)blockIdx.z * HIDDEN * HIDDEN;
    __shared__ float tile[64][65];
    int k0 = blockIdx.x * 64, n0 = blockIdx.y * 64;
    int r = threadIdx.x >> 6, c = threadIdx.x & 63;
    for (int it = 0; it < 16; ++it) {
        int rr = r + 4 * it;
        tile[rr][c] = W[(size_t)(k0 + rr) * HIDDEN + n0 + c];
    }
    __syncthreads();
    for (int it = 0; it < 16; ++it) {
        int rr = r + 4 * it;
        out[(size_t)(n0 + rr) * HIDDEN + k0 + c] = f32_to_bf16_rne(tile[c][rr]);
    }
}

// ---------------------------------------------------------------------------
// Kernel 1: TRANSPOSED K/V projection, FUSED fp32->bf16 for X:
//   KT[z][n][s_glob] = (X@W^T+b)[s][n].  A = Wt rows (global_load_lds, bf16),
//   B = X rows read DIRECTLY as fp32 and reg-staged: 2x float4 load ->
//   v_cvt_pk_bf16_f32 x4 -> ds_write_b128 into the SAME XOR-swizzled slot the
//   fragment reads expect (per-lane write -> swizzle freedom; wave-uniform
//   global_load_lds restriction doesn't apply to this operand).
//   Deletes the standalone cvt kernel (-150 MB HBM round-trip).
//   XCD-aware 1-D grid kept from R10 (FETCH 133->33 MB, verified):
//     i = (y&7) + 8*(m + 8*((y>>3) + 8*z)), bijective on [0,1024).
// ---------------------------------------------------------------------------
__global__ __launch_bounds__(256) void proj_gemm_t(const float* __restrict__ Xk,
                                                   const float* __restrict__ Xv,
                                                   const uint16_t* __restrict__ Wt,
                                                   const float* __restrict__ Bk,
                                                   const float* __restrict__ Bv,
                                                   uint16_t* __restrict__ KT) {
    // decode XCD-swizzled linear block id
    const int i = blockIdx.x;
    const int xcd = i & 7;
    const int slot = i >> 3;
    const int mt = slot & 7;          // m-tile (n-dim), 0..7
    const int yhi = (slot >> 3) & 7;  // upper 3 bits of s-tile
    const int z = slot >> 6;          // 0=K, 1=V
    const int yt = xcd + 8 * yhi;     // s-tile, 0..63

    const uint16_t* A = Wt + (size_t)z * HIDDEN * HIDDEN; // rows: n, len 1024
    const float* B32 = z == 0 ? Xk : Xv;                  // rows: s, fp32
    const float* bias = z == 0 ? Bk : Bv;
    uint16_t* out = KT + (size_t)z * ROWS * HIDDEN;       // [n][8192]

    __shared__ uint16_t slds[16384]; // A: [0,8192), B: [8192,16384)

    const int tid = threadIdx.x;
    const int lane = tid & 63;
    const int w = tid >> 6;
    const int wm = (w >> 1) * 64;
    const int wn = (w & 1) * 64;
    const int m_lane = lane & 15;
    const int kq = lane >> 4;
    const int m0 = mt * 128; // n-dim tile
    const int n0 = yt * 128; // s-dim tile

    f32x4 acc[4][4] = {};

    for (int kb = 0; kb < HIDDEN; kb += 64) {
        // A (Wt, bf16): async global -> LDS, unchanged verified path
        for (int t = 0; t < 4; ++t) {
            int gbase = (w * 4 + t) * 64;
            int g = gbase + lane;
            int r = g >> 3;
            int c = (g & 7) ^ (r & 7);
            const uint16_t* srcA = A + (size_t)(m0 + r) * HIDDEN + kb + c * 8;
            __builtin_amdgcn_global_load_lds(
                (const __attribute__((address_space(1))) uint32_t*)srcA,
                (__attribute__((address_space(3))) uint32_t*)(&slds[gbase * 8]),
                16, 0, 0);
        }
        // B (X, fp32): reg-stage in pairs (2 chunks in flight), convert, write
        for (int tp = 0; tp < 2; ++tp) {
            float4 fa[2][2];
            int gs[2];
#pragma unroll
            for (int u = 0; u < 2; ++u) {
                int t = tp * 2 + u;
                int g = (w * 4 + t) * 64 + lane;
                int r = g >> 3;
                int c = (g & 7) ^ (r & 7);
                const float* src = B32 + (size_t)(n0 + r) * HIDDEN + kb + c * 8;
                fa[u][0] = *(const float4*)src;
                fa[u][1] = *(const float4*)(src + 4);
                gs[u] = g;
            }
#pragma unroll
            for (int u = 0; u < 2; ++u) {
                uint4 pk;
                pk.x = cvt_pk_bf16(fa[u][0].x, fa[u][0].y);
                pk.y = cvt_pk_bf16(fa[u][0].z, fa[u][0].w);
                pk.z = cvt_pk_bf16(fa[u][1].x, fa[u][1].y);
                pk.w = cvt_pk_bf16(fa[u][1].z, fa[u][1].w);
                *(uint4*)(&slds[8192 + gs[u] * 8]) = pk;
            }
        }
        __syncthreads();
        for (int ks = 0; ks < 2; ++ks) {
            int cbase = ks * 4 + kq;
            bf16x8 af[4], bfr[4];
            for (int i2 = 0; i2 < 4; ++i2) {
                int r = wm + i2 * 16 + m_lane;
                int p = cbase ^ (r & 7);
                af[i2] = *(const bf16x8*)(&slds[r * 64 + p * 8]);
            }
            for (int j = 0; j < 4; ++j) {
                int nr = wn + j * 16 + m_lane;
                int p = cbase ^ (nr & 7);
                bfr[j] = *(const bf16x8*)(&slds[8192 + nr * 64 + p * 8]);
            }
            for (int i2 = 0; i2 < 4; ++i2)
                for (int j = 0; j < 4; ++j)
                    acc[i2][j] = __builtin_amdgcn_mfma_f32_16x16x32_bf16(
                        af[i2], bfr[j], acc[i2][j], 0, 0, 0);
        }
        __syncthreads();
    }

    // C write: row = n (bias per row), col = global s. Same C/D mapping.
    for (int i2 = 0; i2 < 4; ++i2) {
        for (int rg = 0; rg < 4; ++rg) {
            int row = m0 + wm + i2 * 16 + kq * 4 + rg;
            float bj = bias[row];
            for (int j = 0; j < 4; ++j) {
                int col = n0 + wn + j * 16 + m_lane;
                out[(size_t)row * ROWS + col] = f32_to_bf16_rne(acc[i2][j][rg] + bj);
            }
        }
    }
}

// ---------------------------------------------------------------------------
// Kernel 2: MFMA K^T V.  P[bh][sc][i][j] = 0.125 * sum_{s in chunk}
//   KT[h*64+i][b*2048+sc*256+s] * VT[h*64+j][...]   (both s-contiguous).
//   (Verified R9/R10.)
// ---------------------------------------------------------------------------
__global__ __launch_bounds__(256) void kv_mfma(const uint16_t* __restrict__ KT,
                                               float* __restrict__ P) {
    const int bh = blockIdx.x;  // b*16+h
    const int sc = blockIdx.y;  // 0..7, 256 s each
    const int b = bh >> 4, h = bh & 15;
    const uint16_t* Kb = KT + (size_t)(h * 64) * ROWS + (size_t)b * SEQ + sc * 256;
    const uint16_t* Vb = Kb + (size_t)HIDDEN * ROWS; // z=1 plane

    __shared__ uint16_t slds[8192]; // A: [0,4096), B: [4096,8192) elems

    const int tid = threadIdx.x;
    const int lane = tid & 63;
    const int w = tid >> 6;      // wave owns output rows w*16..w*16+15
    const int m_lane = lane & 15;
    const int kq = lane >> 4;

    f32x4 acc[4] = {};

    for (int kb = 0; kb < 256; kb += 64) {
        for (int t = 0; t < 2; ++t) {
            int g = t * 256 + tid; // chunk id in [0,512): r = row (64), 8 chunks/row
            int r = g >> 3;
            int c = (g & 7) ^ (r & 7);
            const uint16_t* srcA = Kb + (size_t)r * ROWS + kb + c * 8;
            __builtin_amdgcn_global_load_lds(
                (const __attribute__((address_space(1))) uint32_t*)srcA,
                (__attribute__((address_space(3))) uint32_t*)(&slds[g * 8]),
                16, 0, 0);
            const uint16_t* srcB = Vb + (size_t)r * ROWS + kb + c * 8;
            __builtin_amdgcn_global_load_lds(
                (const __attribute__((address_space(1))) uint32_t*)srcB,
                (__attribute__((address_space(3))) uint32_t*)(&slds[4096 + g * 8]),
                16, 0, 0);
        }
        __syncthreads();
        for (int ks = 0; ks < 2; ++ks) {
            int cbase = ks * 4 + kq;
            int ar = w * 16 + m_lane;
            bf16x8 af = *(const bf16x8*)(&slds[ar * 64 + (cbase ^ (ar & 7)) * 8]);
            for (int j = 0; j < 4; ++j) {
                int br = j * 16 + m_lane;
                bf16x8 bf_ = *(const bf16x8*)(&slds[4096 + br * 64 + (cbase ^ (br & 7)) * 8]);
                acc[j] = __builtin_amdgcn_mfma_f32_16x16x32_bf16(af, bf_, acc[j], 0, 0, 0);
            }
        }
        __syncthreads();
    }

    float* Pp = P + ((size_t)bh * 8 + sc) * 4096;
    for (int j = 0; j < 4; ++j) {
        for (int rg = 0; rg < 4; ++rg) {
            int row = w * 16 + kq * 4 + rg;
            int col = j * 16 + m_lane;
            Pp[row * 64 + col] = acc[j][rg] * 0.125f;
        }
    }
}

// ---------------------------------------------------------------------------
// Kernel 3: fold M into weights — PER BATCH. Sums the 8 kv partials inline.
// ---------------------------------------------------------------------------
__global__ __launch_bounds__(256) void wprime_kernel(const float* __restrict__ Wq,
                                                     const float* __restrict__ bq,
                                                     const float* __restrict__ P,
                                                     uint16_t* __restrict__ Wpt,
                                                     float* __restrict__ bp) {
    const int h = blockIdx.x;
    const int r0 = blockIdx.y * 64;
    const int b = blockIdx.z;
    const int tid = threadIdx.x;

    __shared__ float Mh[64][65];
    __shared__ float Wl[64][65];
    const float* Pp = P + ((size_t)(b * 16 + h)) * 8 * 4096;
    for (int it = 0; it < 16; ++it) {
        int e = it * 256 + tid;
        int a = e >> 6, c = e & 63;
        float s = 0.f;
        for (int sc = 0; sc < 8; ++sc) s += Pp[sc * 4096 + e];
        Mh[a][c] = s;
        Wl[a][c] = Wq[(size_t)(r0 + a) * HIDDEN + h * 64 + c];
    }
    __syncthreads();

    const int r = tid & 63;
    const int jbase = tid >> 6; // 0..3
    float acc[16] = {};
    for (int i = 0; i < 64; ++i) {
        float wv = Wl[r][i];
        for (int jj = 0; jj < 16; ++jj)
            acc[jj] += wv * Mh[i][jbase + 4 * jj];
    }
    uint16_t* Wb = Wpt + (size_t)b * HIDDEN * HIDDEN;
    for (int jj = 0; jj < 16; ++jj) {
        int n = h * 64 + jbase + 4 * jj;
        Wb[(size_t)n * HIDDEN + r0 + r] = f32_to_bf16_rne(acc[jj]);
    }

    if (blockIdx.y == 0 && tid < 64) {
        int j = tid;
        float s = 0.f;
        for (int i = 0; i < 64; ++i) s += bq[h * 64 + i] * Mh[i][j];
        bp[b * HIDDEN + h * 64 + j] = s;
    }
}

// ---------------------------------------------------------------------------
// Kernel 4: out = Xq @ W'_b^T + b'_b, FUSED fp32 A: Xq read directly as fp32,
//   reg-staged + cvt_pk -> LDS (same swizzled slots). B = Wpt global_load_lds.
// ---------------------------------------------------------------------------
__global__ __launch_bounds__(256) void final_gemm(const float* __restrict__ Xq,
                                                  const uint16_t* __restrict__ Wpt,
                                                  const float* __restrict__ bp,
                                                  float* __restrict__ out) {
    __shared__ uint16_t slds[16384];

    const int tid = threadIdx.x;
    const int lane = tid & 63;
    const int w = tid >> 6;
    const int wm = (w >> 1) * 64;
    const int wn = (w & 1) * 64;
    const int m_lane = lane & 15;
    const int kq = lane >> 4;
    const int m0 = blockIdx.x * 128;
    const int n0 = blockIdx.y * 128;
    const int batch = m0 >> 11;
    const uint16_t* W = Wpt + (size_t)batch * HIDDEN * HIDDEN;
    const float* bias = bp + batch * HIDDEN;

    f32x4 acc[4][4] = {};

    for (int kb = 0; kb < HIDDEN; kb += 64) {
        // B (Wpt, bf16): async global -> LDS
        for (int t = 0; t < 4; ++t) {
            int gbase = (w * 4 + t) * 64;
            int g = gbase + lane;
            int r = g >> 3;
            int c = (g & 7) ^ (r & 7);
            const uint16_t* srcB = W + (size_t)(n0 + r) * HIDDEN + kb + c * 8;
            __builtin_amdgcn_global_load_lds(
                (const __attribute__((address_space(1))) uint32_t*)srcB,
                (__attribute__((address_space(3))) uint32_t*)(&slds[8192 + gbase * 8]),
                16, 0, 0);
        }
        // A (Xq, fp32): reg-stage pairs, convert, swizzled ds_write
        for (int tp = 0; tp < 2; ++tp) {
            float4 fa[2][2];
            int gs[2];
#pragma unroll
            for (int u = 0; u < 2; ++u) {
                int t = tp * 2 + u;
                int g = (w * 4 + t) * 64 + lane;
                int r = g >> 3;
                int c = (g & 7) ^ (r & 7);
                const float* src = Xq + (size_t)(m0 + r) * HIDDEN + kb + c * 8;
                fa[u][0] = *(const float4*)src;
                fa[u][1] = *(const float4*)(src + 4);
                gs[u] = g;
            }
#pragma unroll
            for (int u = 0; u < 2; ++u) {
                uint4 pk;
                pk.x = cvt_pk_bf16(fa[u][0].x, fa[u][0].y);
                pk.y = cvt_pk_bf16(fa[u][0].z, fa[u][0].w);
                pk.z = cvt_pk_bf16(fa[u][1].x, fa[u][1].y);
                pk.w = cvt_pk_bf16(fa[u][1].z, fa[u][1].w);
                *(uint4*)(&slds[gs[u] * 8]) = pk;
            }
        }
        __syncthreads();
        for (int ks = 0; ks < 2; ++ks) {
            int cbase = ks * 4 + kq;
            bf16x8 af[4], bfr[4];
            for (int i = 0; i < 4; ++i) {
                int r = wm + i * 16 + m_lane;
                int p = cbase ^ (r & 7);
                af[i] = *(const bf16x8*)(&slds[r * 64 + p * 8]);
            }
            for (int j = 0; j < 4; ++j) {
                int nr = wn + j * 16 + m_lane;
                int p = cbase ^ (nr & 7);
                bfr[j] = *(const bf16x8*)(&slds[8192 + nr * 64 + p * 8]);
            }
            for (int i = 0; i < 4; ++i)
                for (int j = 0; j < 4; ++j)
                    acc[i][j] = __builtin_amdgcn_mfma_f32_16x16x32_bf16(
                        af[i], bfr[j], acc[i][j], 0, 0, 0);
        }
        __syncthreads();
    }

    for (int j = 0; j < 4; ++j) {
        int col = n0 + wn + j * 16 + m_lane;
        float bj = bias[col];
        for (int i = 0; i < 4; ++i) {
            int rbase = m0 + wm + i * 16 + kq * 4;
            for (int rg = 0; rg < 4; ++rg)
                out[(size_t)(rbase + rg) * HIDDEN + col] = acc[i][j][rg] + bj;
        }
    }
}

// ---------------------------------------------------------------------------
extern "C" void kernel_launch(void* const* d_in, const int* in_sizes, int n_in,
                              void* d_out, int out_size, void* d_ws, size_t ws_size,
                              hipStream_t stream) {
    const float* Xq = (const float*)d_in[0];
    const float* Xk = (const float*)d_in[1];
    const float* Xv = (const float*)d_in[2];
    const float* Wq = (const float*)d_in[3];
    const float* Bq = (const float*)d_in[4];
    const float* Wk = (const float*)d_in[5];
    const float* Bk = (const float*)d_in[6];
    const float* Wv = (const float*)d_in[7];
    const float* Bv = (const float*)d_in[8];
    float* out = (float*)d_out;

    char* ws = (char*)d_ws;
    uint16_t* KT = (uint16_t*)ws;                   // 33,554,432 B (K^T,V^T bf16)
    uint16_t* Wt = (uint16_t*)(ws + 33554432);      //  4,194,304 B (Wk,Wv bf16 T)
    float* P = (float*)(ws + 37748736);             //  8,388,608 B (64bh x 8sc x 4096)
    uint16_t* Wpt = (uint16_t*)(ws + 46137344);     //  8,388,608 B (4 x W'_b)
    float* bp = (float*)(ws + 54525952);            //     16,384 B (~54.5 MB)

    wt_kernel<<<dim3(16, 16, 2), 256, 0, stream>>>(Wk, Wv, Wt);
    // XCD-swizzled 1-D grid: 1024 blocks, i = (y&7) + 8*(m + 8*((y>>3) + 8*z)).
    proj_gemm_t<<<dim3(1024), 256, 0, stream>>>(Xk, Xv, Wt, Bk, Bv, KT);
    kv_mfma<<<dim3(64, 8), 256, 0, stream>>>(KT, P);
    wprime_kernel<<<dim3(16, 16, 4), 256, 0, stream>>>(Wq, Bq, P, Wpt, bp);
    final_gemm<<<dim3(64, 8), 256, 0, stream>>>(Xq, Wpt, bp, out);
}

// Round 12
// 268.584 us; speedup vs baseline: 1.0014x; 1.0014x over previous
//
#include <hip/hip_runtime.h>
#include <stdint.h>

#define HIDDEN 1024
#define HEADS 16
#define HEAD_DIM 64
#define BATCH 4
#define SEQ 2048
#define ROWS (BATCH * SEQ) /* 8192 */

typedef float f32x4 __attribute__((ext_vector_type(4)));
typedef short bf16x8 __attribute__((ext_vector_type(8))); // 8 bf16 = 4 VGPRs

__device__ __forceinline__ uint16_t f32_to_bf16_rne(float f) {
    uint32_t u = __float_as_uint(f);
    uint32_t r = u + 0x7FFFu + ((u >> 16) & 1u);
    return (uint16_t)(r >> 16);
}
__device__ __forceinline__ float bf16_to_f32(uint16_t u) {
    return __uint_as_float(((uint32_t)u) << 16);
}
// HW packed fp32->bf16 RNE: dst = {bf16(lo), bf16(hi)} (lo in bits 0-15).
__device__ __forceinline__ uint32_t cvt_pk_bf16(float lo, float hi) {
    uint32_t r;
    asm("v_cvt_pk_bf16_f32 %0, %1, %2" : "=v"(r) : "v"(lo), "v"(hi));
    return r;
}

// ---------------------------------------------------------------------------
// Kernel 0: W[K][N] fp32 -> Wt[N][K] bf16, z in {Wk, Wv} only (Wq stays fp32)
// ---------------------------------------------------------------------------
__global__ __launch_bounds__(256) void wt_kernel(const float* __restrict__ Wk,
                                                 const float* __restrict__ Wv,
                                                 uint16_t* __restrict__ Wt) {
    const float* W = blockIdx.z == 0 ? Wk : Wv;
    uint16_t* out = Wt + (size_t)blockIdx.z * HIDDEN * HIDDEN;
    __shared__ float tile[64][65];
    int k0 = blockIdx.x * 64, n0 = blockIdx.y * 64;
    int r = threadIdx.x >> 6, c = threadIdx.x & 63;
    for (int it = 0; it < 16; ++it) {
        int rr = r + 4 * it;
        tile[rr][c] = W[(size_t)(k0 + rr) * HIDDEN + n0 + c];
    }
    __syncthreads();
    for (int it = 0; it < 16; ++it) {
        int rr = r + 4 * it;
        out[(size_t)(n0 + rr) * HIDDEN + k0 + c] = f32_to_bf16_rne(tile[c][rr]);
    }
}

// ---------------------------------------------------------------------------
// Kernel 1: TRANSPOSED K/V projection, FUSED fp32->bf16 for X.
//   R11 POST-MORTEM FIX: the fp32 reg-stage loads are now issued BEFORE the
//   global_load_lds batch. vmcnt is issue-ordered (waiting for the newest
//   load drains all prior ones) -> R11's order forced a full vmcnt(0) drain
//   of the async A-staging queue every K-step before the barrier (+33 us,
//   VALUBusy DOWN 33->22%). With fp32 first, the wait before cvt_pk is
//   vmcnt(4): the 4 A-loads stay in flight through cvt+ds_write, drained at
//   the barrier exactly as in the verified R10 schedule.
//   XCD-aware 1-D grid kept from R10 (FETCH 133->33 MB, verified):
//     i = (y&7) + 8*(m + 8*((y>>3) + 8*z)), bijective on [0,1024).
// ---------------------------------------------------------------------------
__global__ __launch_bounds__(256) void proj_gemm_t(const float* __restrict__ Xk,
                                                   const float* __restrict__ Xv,
                                                   const uint16_t* __restrict__ Wt,
                                                   const float* __restrict__ Bk,
                                                   const float* __restrict__ Bv,
                                                   uint16_t* __restrict__ KT) {
    // decode XCD-swizzled linear block id
    const int i = blockIdx.x;
    const int xcd = i & 7;
    const int slot = i >> 3;
    const int mt = slot & 7;          // m-tile (n-dim), 0..7
    const int yhi = (slot >> 3) & 7;  // upper 3 bits of s-tile
    const int z = slot >> 6;          // 0=K, 1=V
    const int yt = xcd + 8 * yhi;     // s-tile, 0..63

    const uint16_t* A = Wt + (size_t)z * HIDDEN * HIDDEN; // rows: n, len 1024
    const float* B32 = z == 0 ? Xk : Xv;                  // rows: s, fp32
    const float* bias = z == 0 ? Bk : Bv;
    uint16_t* out = KT + (size_t)z * ROWS * HIDDEN;       // [n][8192]

    __shared__ uint16_t slds[16384]; // A: [0,8192), B: [8192,16384)

    const int tid = threadIdx.x;
    const int lane = tid & 63;
    const int w = tid >> 6;
    const int wm = (w >> 1) * 64;
    const int wn = (w & 1) * 64;
    const int m_lane = lane & 15;
    const int kq = lane >> 4;
    const int m0 = mt * 128; // n-dim tile
    const int n0 = yt * 128; // s-dim tile

    f32x4 acc[4][4] = {};

    for (int kb = 0; kb < HIDDEN; kb += 64) {
        // B (X, fp32): issue reg-stage loads FIRST (oldest in vmcnt queue)
        float4 fa[4][2];
        int gs[4];
#pragma unroll
        for (int u = 0; u < 4; ++u) {
            int g = (w * 4 + u) * 64 + lane;
            int r = g >> 3;
            int c = (g & 7) ^ (r & 7);
            const float* src = B32 + (size_t)(n0 + r) * HIDDEN + kb + c * 8;
            fa[u][0] = *(const float4*)src;
            fa[u][1] = *(const float4*)(src + 4);
            gs[u] = g;
        }
        // A (Wt, bf16): async global -> LDS issued AFTER (stay in flight
        // through the cvt/ds_write below; drained only at the barrier)
        for (int t = 0; t < 4; ++t) {
            int gbase = (w * 4 + t) * 64;
            int g = gbase + lane;
            int r = g >> 3;
            int c = (g & 7) ^ (r & 7);
            const uint16_t* srcA = A + (size_t)(m0 + r) * HIDDEN + kb + c * 8;
            __builtin_amdgcn_global_load_lds(
                (const __attribute__((address_space(1))) uint32_t*)srcA,
                (__attribute__((address_space(3))) uint32_t*)(&slds[gbase * 8]),
                16, 0, 0);
        }
        // convert + swizzled ds_write (waits vmcnt(4), not 0)
#pragma unroll
        for (int u = 0; u < 4; ++u) {
            uint4 pk;
            pk.x = cvt_pk_bf16(fa[u][0].x, fa[u][0].y);
            pk.y = cvt_pk_bf16(fa[u][0].z, fa[u][0].w);
            pk.z = cvt_pk_bf16(fa[u][1].x, fa[u][1].y);
            pk.w = cvt_pk_bf16(fa[u][1].z, fa[u][1].w);
            *(uint4*)(&slds[8192 + gs[u] * 8]) = pk;
        }
        __syncthreads();
        for (int ks = 0; ks < 2; ++ks) {
            int cbase = ks * 4 + kq;
            bf16x8 af[4], bfr[4];
            for (int i2 = 0; i2 < 4; ++i2) {
                int r = wm + i2 * 16 + m_lane;
                int p = cbase ^ (r & 7);
                af[i2] = *(const bf16x8*)(&slds[r * 64 + p * 8]);
            }
            for (int j = 0; j < 4; ++j) {
                int nr = wn + j * 16 + m_lane;
                int p = cbase ^ (nr & 7);
                bfr[j] = *(const bf16x8*)(&slds[8192 + nr * 64 + p * 8]);
            }
            for (int i2 = 0; i2 < 4; ++i2)
                for (int j = 0; j < 4; ++j)
                    acc[i2][j] = __builtin_amdgcn_mfma_f32_16x16x32_bf16(
                        af[i2], bfr[j], acc[i2][j], 0, 0, 0);
        }
        __syncthreads();
    }

    // C write: row = n (bias per row), col = global s. Same C/D mapping.
    for (int i2 = 0; i2 < 4; ++i2) {
        for (int rg = 0; rg < 4; ++rg) {
            int row = m0 + wm + i2 * 16 + kq * 4 + rg;
            float bj = bias[row];
            for (int j = 0; j < 4; ++j) {
                int col = n0 + wn + j * 16 + m_lane;
                out[(size_t)row * ROWS + col] = f32_to_bf16_rne(acc[i2][j][rg] + bj);
            }
        }
    }
}

// ---------------------------------------------------------------------------
// Kernel 2: MFMA K^T V.  P[bh][sc][i][j] = 0.125 * sum_{s in chunk}
//   KT[h*64+i][b*2048+sc*256+s] * VT[h*64+j][...]   (both s-contiguous).
//   (Verified R9/R10.)
// ---------------------------------------------------------------------------
__global__ __launch_bounds__(256) void kv_mfma(const uint16_t* __restrict__ KT,
                                               float* __restrict__ P) {
    const int bh = blockIdx.x;  // b*16+h
    const int sc = blockIdx.y;  // 0..7, 256 s each
    const int b = bh >> 4, h = bh & 15;
    const uint16_t* Kb = KT + (size_t)(h * 64) * ROWS + (size_t)b * SEQ + sc * 256;
    const uint16_t* Vb = Kb + (size_t)HIDDEN * ROWS; // z=1 plane

    __shared__ uint16_t slds[8192]; // A: [0,4096), B: [4096,8192) elems

    const int tid = threadIdx.x;
    const int lane = tid & 63;
    const int w = tid >> 6;      // wave owns output rows w*16..w*16+15
    const int m_lane = lane & 15;
    const int kq = lane >> 4;

    f32x4 acc[4] = {};

    for (int kb = 0; kb < 256; kb += 64) {
        for (int t = 0; t < 2; ++t) {
            int g = t * 256 + tid; // chunk id in [0,512): r = row (64), 8 chunks/row
            int r = g >> 3;
            int c = (g & 7) ^ (r & 7);
            const uint16_t* srcA = Kb + (size_t)r * ROWS + kb + c * 8;
            __builtin_amdgcn_global_load_lds(
                (const __attribute__((address_space(1))) uint32_t*)srcA,
                (__attribute__((address_space(3))) uint32_t*)(&slds[g * 8]),
                16, 0, 0);
            const uint16_t* srcB = Vb + (size_t)r * ROWS + kb + c * 8;
            __builtin_amdgcn_global_load_lds(
                (const __attribute__((address_space(1))) uint32_t*)srcB,
                (__attribute__((address_space(3))) uint32_t*)(&slds[4096 + g * 8]),
                16, 0, 0);
        }
        __syncthreads();
        for (int ks = 0; ks < 2; ++ks) {
            int cbase = ks * 4 + kq;
            int ar = w * 16 + m_lane;
            bf16x8 af = *(const bf16x8*)(&slds[ar * 64 + (cbase ^ (ar & 7)) * 8]);
            for (int j = 0; j < 4; ++j) {
                int br = j * 16 + m_lane;
                bf16x8 bf_ = *(const bf16x8*)(&slds[4096 + br * 64 + (cbase ^ (br & 7)) * 8]);
                acc[j] = __builtin_amdgcn_mfma_f32_16x16x32_bf16(af, bf_, acc[j], 0, 0, 0);
            }
        }
        __syncthreads();
    }

    float* Pp = P + ((size_t)bh * 8 + sc) * 4096;
    for (int j = 0; j < 4; ++j) {
        for (int rg = 0; rg < 4; ++rg) {
            int row = w * 16 + kq * 4 + rg;
            int col = j * 16 + m_lane;
            Pp[row * 64 + col] = acc[j][rg] * 0.125f;
        }
    }
}

// ---------------------------------------------------------------------------
// Kernel 3: fold M into weights — PER BATCH. Sums the 8 kv partials inline.
// ---------------------------------------------------------------------------
__global__ __launch_bounds__(256) void wprime_kernel(const float* __restrict__ Wq,
                                                     const float* __restrict__ bq,
                                                     const float* __restrict__ P,
                                                     uint16_t* __restrict__ Wpt,
                                                     float* __restrict__ bp) {
    const int h = blockIdx.x;
    const int r0 = blockIdx.y * 64;
    const int b = blockIdx.z;
    const int tid = threadIdx.x;

    __shared__ float Mh[64][65];
    __shared__ float Wl[64][65];
    const float* Pp = P + ((size_t)(b * 16 + h)) * 8 * 4096;
    for (int it = 0; it < 16; ++it) {
        int e = it * 256 + tid;
        int a = e >> 6, c = e & 63;
        float s = 0.f;
        for (int sc = 0; sc < 8; ++sc) s += Pp[sc * 4096 + e];
        Mh[a][c] = s;
        Wl[a][c] = Wq[(size_t)(r0 + a) * HIDDEN + h * 64 + c];
    }
    __syncthreads();

    const int r = tid & 63;
    const int jbase = tid >> 6; // 0..3
    float acc[16] = {};
    for (int i = 0; i < 64; ++i) {
        float wv = Wl[r][i];
        for (int jj = 0; jj < 16; ++jj)
            acc[jj] += wv * Mh[i][jbase + 4 * jj];
    }
    uint16_t* Wb = Wpt + (size_t)b * HIDDEN * HIDDEN;
    for (int jj = 0; jj < 16; ++jj) {
        int n = h * 64 + jbase + 4 * jj;
        Wb[(size_t)n * HIDDEN + r0 + r] = f32_to_bf16_rne(acc[jj]);
    }

    if (blockIdx.y == 0 && tid < 64) {
        int j = tid;
        float s = 0.f;
        for (int i = 0; i < 64; ++i) s += bq[h * 64 + i] * Mh[i][j];
        bp[b * HIDDEN + h * 64 + j] = s;
    }
}

// ---------------------------------------------------------------------------
// Kernel 4: out = Xq @ W'_b^T + b'_b, FUSED fp32 A with the same ordering
//   fix: fp32 reg-stage loads issued BEFORE the Wpt global_load_lds batch.
// ---------------------------------------------------------------------------
__global__ __launch_bounds__(256) void final_gemm(const float* __restrict__ Xq,
                                                  const uint16_t* __restrict__ Wpt,
                                                  const float* __restrict__ bp,
                                                  float* __restrict__ out) {
    __shared__ uint16_t slds[16384];

    const int tid = threadIdx.x;
    const int lane = tid & 63;
    const int w = tid >> 6;
    const int wm = (w >> 1) * 64;
    const int wn = (w & 1) * 64;
    const int m_lane = lane & 15;
    const int kq = lane >> 4;
    const int m0 = blockIdx.x * 128;
    const int n0 = blockIdx.y * 128;
    const int batch = m0 >> 11;
    const uint16_t* W = Wpt + (size_t)batch * HIDDEN * HIDDEN;
    const float* bias = bp + batch * HIDDEN;

    f32x4 acc[4][4] = {};

    for (int kb = 0; kb < HIDDEN; kb += 64) {
        // A (Xq, fp32): issue reg-stage loads FIRST
        float4 fa[4][2];
        int gs[4];
#pragma unroll
        for (int u = 0; u < 4; ++u) {
            int g = (w * 4 + u) * 64 + lane;
            int r = g >> 3;
            int c = (g & 7) ^ (r & 7);
            const float* src = Xq + (size_t)(m0 + r) * HIDDEN + kb + c * 8;
            fa[u][0] = *(const float4*)src;
            fa[u][1] = *(const float4*)(src + 4);
            gs[u] = g;
        }
        // B (Wpt, bf16): async global -> LDS issued AFTER
        for (int t = 0; t < 4; ++t) {
            int gbase = (w * 4 + t) * 64;
            int g = gbase + lane;
            int r = g >> 3;
            int c = (g & 7) ^ (r & 7);
            const uint16_t* srcB = W + (size_t)(n0 + r) * HIDDEN + kb + c * 8;
            __builtin_amdgcn_global_load_lds(
                (const __attribute__((address_space(1))) uint32_t*)srcB,
                (__attribute__((address_space(3))) uint32_t*)(&slds[8192 + gbase * 8]),
                16, 0, 0);
        }
        // convert + swizzled ds_write (waits vmcnt(4), not 0)
#pragma unroll
        for (int u = 0; u < 4; ++u) {
            uint4 pk;
            pk.x = cvt_pk_bf16(fa[u][0].x, fa[u][0].y);
            pk.y = cvt_pk_bf16(fa[u][0].z, fa[u][0].w);
            pk.z = cvt_pk_bf16(fa[u][1].x, fa[u][1].y);
            pk.w = cvt_pk_bf16(fa[u][1].z, fa[u][1].w);
            *(uint4*)(&slds[gs[u] * 8]) = pk;
        }
        __syncthreads();
        for (int ks = 0; ks < 2; ++ks) {
            int cbase = ks * 4 + kq;
            bf16x8 af[4], bfr[4];
            for (int i = 0; i < 4; ++i) {
                int r = wm + i * 16 + m_lane;
                int p = cbase ^ (r & 7);
                af[i] = *(const bf16x8*)(&slds[r * 64 + p * 8]);
            }
            for (int j = 0; j < 4; ++j) {
                int nr = wn + j * 16 + m_lane;
                int p = cbase ^ (nr & 7);
                bfr[j] = *(const bf16x8*)(&slds[8192 + nr * 64 + p * 8]);
            }
            for (int i = 0; i < 4; ++i)
                for (int j = 0; j < 4; ++j)
                    acc[i][j] = __builtin_amdgcn_mfma_f32_16x16x32_bf16(
                        af[i], bfr[j], acc[i][j], 0, 0, 0);
        }
        __syncthreads();
    }

    for (int j = 0; j < 4; ++j) {
        int col = n0 + wn + j * 16 + m_lane;
        float bj = bias[col];
        for (int i = 0; i < 4; ++i) {
            int rbase = m0 + wm + i * 16 + kq * 4;
            for (int rg = 0; rg < 4; ++rg)
                out[(size_t)(rbase + rg) * HIDDEN + col] = acc[i][j][rg] + bj;
        }
    }
}

// ---------------------------------------------------------------------------
extern "C" void kernel_launch(void* const* d_in, const int* in_sizes, int n_in,
                              void* d_out, int out_size, void* d_ws, size_t ws_size,
                              hipStream_t stream) {
    const float* Xq = (const float*)d_in[0];
    const float* Xk = (const float*)d_in[1];
    const float* Xv = (const float*)d_in[2];
    const float* Wq = (const float*)d_in[3];
    const float* Bq = (const float*)d_in[4];
    const float* Wk = (const float*)d_in[5];
    const float* Bk = (const float*)d_in[6];
    const float* Wv = (const float*)d_in[7];
    const float* Bv = (const float*)d_in[8];
    float* out = (float*)d_out;

    char* ws = (char*)d_ws;
    uint16_t* KT = (uint16_t*)ws;                   // 33,554,432 B (K^T,V^T bf16)
    uint16_t* Wt = (uint16_t*)(ws + 33554432);      //  4,194,304 B (Wk,Wv bf16 T)
    float* P = (float*)(ws + 37748736);             //  8,388,608 B (64bh x 8sc x 4096)
    uint16_t* Wpt = (uint16_t*)(ws + 46137344);     //  8,388,608 B (4 x W'_b)
    float* bp = (float*)(ws + 54525952);            //     16,384 B (~54.5 MB)

    wt_kernel<<<dim3(16, 16, 2), 256, 0, stream>>>(Wk, Wv, Wt);
    // XCD-swizzled 1-D grid: 1024 blocks, i = (y&7) + 8*(m + 8*((y>>3) + 8*z)).
    proj_gemm_t<<<dim3(1024), 256, 0, stream>>>(Xk, Xv, Wt, Bk, Bv, KT);
    kv_mfma<<<dim3(64, 8), 256, 0, stream>>>(KT, P);
    wprime_kernel<<<dim3(16, 16, 4), 256, 0, stream>>>(Wq, Bq, P, Wpt, bp);
    final_gemm<<<dim3(64, 8), 256, 0, stream>>>(Xq, Wpt, bp, out);
}